// Round 10
// baseline (206.834 us; speedup 1.0000x reference)
//
#include <hip/hip_runtime.h>

// PSROI pooling: fsam (N=8, C=245, H=80, W=80) f32, box (R=8192, 5) f32
// out (R, 245) f32. out[r, c] = mean over fsam[b, c, hs:he, ws:we].
//
// ROUND-10: bin = roi * fl32(1/7)  (ARCP reciprocal-multiply — CONFIRMED by
// R9: switching to it moved absmax 1.84375 -> 1.20117, the only movement in
// 9 rounds), edges = SEPARATELY-ROUNDED mul then add (the last untested
// cell of the {div,rcp} x {fma,sep} matrix; R9's fma variant left 1.20 of
// residual flips). Separation enforced with asm barriers — R5 proved
// source-level pragmas are ignored by the harness's fast-math build.

#define N_ 8
#define C_ 245
#define H_ 80
#define W_ 80
#define R_ 8192
#define P_ 7

// numpy/XLA-style separately-rounded g*bin + off in f32; barriers forbid
// both FMA contraction and reassociation through these values.
__device__ __forceinline__ float sep_ma(float a, float b, float c) {
    float p = a * b;                 // v_mul_f32, IEEE RN
    asm volatile("" : "+v"(p));      // contraction barrier
    float s = p + c;                 // v_add_f32, IEEE RN
    asm volatile("" : "+v"(s));
    return s;
}

__global__ __launch_bounds__(256) void psroi_kernel(
    const float* __restrict__ fsam,
    const float* __restrict__ box,
    float* __restrict__ out)
{
    int idx = blockIdx.x * 256 + threadIdx.x;
    if (idx >= R_ * C_) return;

    int r = idx / C_;
    int c = idx - r * C_;          // fsam channel == flat output channel
    int pw = c % P_;
    int ph = (c / P_) % P_;

    const float* bx = box + (size_t)r * 5;
    int   b  = (int)bx[0];
    float x1 = rintf(bx[1]);               // np.round half-even, exact ints
    float y1 = rintf(bx[2]);
    float x2 = rintf(bx[3] + 1.0f);
    float y2 = rintf(bx[4] + 1.0f);

    float roi_w = fmaxf(x2 - x1, 0.1f);
    float roi_h = fmaxf(y2 - y1, 0.1f);

    // ARCP: /7 compiled as multiply by fl32(1/7) = 0x3E124925 (rounds up).
    const float RCP7 = __uint_as_float(0x3E124925u);
    float bin_w = roi_w * RCP7;            // single rounding, biased high
    float bin_h = roi_h * RCP7;
    asm volatile("" : "+v"(bin_w), "+v"(bin_h));  // pin: no reassociation

    // edges: floor/ceil of SEPARATELY-rounded g*bin + off.
    float hs_f = floorf(sep_ma((float)ph,       bin_h, y1));
    float he_f = ceilf (sep_ma((float)(ph + 1), bin_h, y1));
    float ws_f = floorf(sep_ma((float)pw,       bin_w, x1));
    float we_f = ceilf (sep_ma((float)(pw + 1), bin_w, x1));

    int hs = (int)fminf(fmaxf(hs_f, 0.0f), 80.0f);
    int he = (int)fminf(fmaxf(he_f, 0.0f), 80.0f);
    int ws = (int)fminf(fmaxf(ws_f, 0.0f), 80.0f);
    int we = (int)fminf(fmaxf(we_f, 0.0f), 80.0f);

    const float* plane = fsam + ((size_t)b * C_ + c) * (H_ * W_);

    float s = 0.0f;
    for (int y = hs; y < he; ++y) {
        const float* row = plane + y * W_;
        for (int x = ws; x < we; ++x) {
            s += row[x];
        }
    }

    int area = (he - hs) * (we - ws);
    out[idx] = (area > 0) ? s / (float)area : 0.0f;
}

extern "C" void kernel_launch(void* const* d_in, const int* in_sizes, int n_in,
                              void* d_out, int out_size, void* d_ws, size_t ws_size,
                              hipStream_t stream) {
    const float* fsam = (const float*)d_in[0];
    const float* box  = (const float*)d_in[1];
    float* out = (float*)d_out;

    int total = R_ * C_;                 // 2,007,040
    int grid = (total + 255) / 256;      // 7840
    psroi_kernel<<<grid, 256, 0, stream>>>(fsam, box, out);
}

// Round 11
// 104.022 us; speedup vs baseline: 1.9884x; 1.9884x over previous
//
#include <hip/hip_runtime.h>

// PSROI pooling: fsam (N=8, C=245, H=80, W=80) f32, box (R=8192, 5) f32
// out (R, 245) f32. out[r, c] = mean over fsam[b, c, hs:he, ws:we].
//
// ARITHMETIC (frozen since R10, DO NOT TOUCH): bin = roi * fl32(1/7)
// (reciprocal multiply, 0x3E124925) and edges = SEPARATELY-rounded
// g*bin + off (asm barriers). This exactly matches the reference output
// (absmax 0.015625 <= 0.0725). All other variants fail.
//
// R11 CHANGE (layout only): block = (one channel c, 256 consecutive ROIs)
// instead of thread=(r-major,c-minor). Old mapping: a wave touched 64
// different 25.6KB planes -> 13x read amplification (FETCH 645 MB vs 49 MB
// input). New mapping: block working set = <=8 planes (one channel, 8
// images) = 205 KB; XCD swizzle pins channel-groups of 16 to one XCD
// (round-robin id%8), so concurrent per-XCD working set ~1.6 MB (L2-fit)
// and out[r, c..c+15] lines assemble within one XCD's L2.

#define C_ 245
#define H_ 80
#define W_ 80
#define R_ 8192
#define P_ 7

// XLA-style separately-rounded a*b + c in f32; barriers forbid contraction.
__device__ __forceinline__ float sep_ma(float a, float b, float c) {
    float p = a * b;                 // v_mul_f32, IEEE RN
    asm volatile("" : "+v"(p));      // contraction barrier
    float s = p + c;                 // v_add_f32, IEEE RN
    asm volatile("" : "+v"(s));
    return s;
}

__global__ __launch_bounds__(256) void psroi_kernel(
    const float* __restrict__ fsam,
    const float* __restrict__ box,
    float* __restrict__ out)
{
    // ---- swizzled block decode: XCD j <- channel groups {j, j+8} ----
    // grid = 8192; XCD = blockIdx.x % 8 under round-robin dispatch.
    int id = blockIdx.x;
    int j  = id & 7;
    int m  = id >> 3;                 // 0..1023 within XCD
    int g  = (m < 512) ? j : j + 8;   // channel group (16 channels each)
    int l  = (m < 512) ? m : m - 512; // 0..511 within group
    int c    = g * 16 + (l >> 5);     // channel
    int rblk = l & 31;                // 32 r-blocks of 256 ROIs
    if (c >= C_) return;              // padding (group 15 has 5 channels)

    int r = rblk * 256 + (int)threadIdx.x;

    int pw = c % P_;
    int ph = (c / P_) % P_;

    // ---- R10-frozen edge arithmetic ----
    const float* bx = box + (size_t)r * 5;
    int   b  = (int)bx[0];
    float x1 = rintf(bx[1]);               // np.round half-even, exact ints
    float y1 = rintf(bx[2]);
    float x2 = rintf(bx[3] + 1.0f);
    float y2 = rintf(bx[4] + 1.0f);

    float roi_w = fmaxf(x2 - x1, 0.1f);
    float roi_h = fmaxf(y2 - y1, 0.1f);

    const float RCP7 = __uint_as_float(0x3E124925u);  // fl32(1/7), rounds up
    float bin_w = roi_w * RCP7;
    float bin_h = roi_h * RCP7;
    asm volatile("" : "+v"(bin_w), "+v"(bin_h));      // pin: no reassociation

    float hs_f = floorf(sep_ma((float)ph,       bin_h, y1));
    float he_f = ceilf (sep_ma((float)(ph + 1), bin_h, y1));
    float ws_f = floorf(sep_ma((float)pw,       bin_w, x1));
    float we_f = ceilf (sep_ma((float)(pw + 1), bin_w, x1));

    int hs = (int)fminf(fmaxf(hs_f, 0.0f), 80.0f);
    int he = (int)fminf(fmaxf(he_f, 0.0f), 80.0f);
    int ws = (int)fminf(fmaxf(ws_f, 0.0f), 80.0f);
    int we = (int)fminf(fmaxf(we_f, 0.0f), 80.0f);

    const float* plane = fsam + ((size_t)b * C_ + c) * (H_ * W_);

    float s = 0.0f;
    for (int y = hs; y < he; ++y) {
        const float* row = plane + y * W_;
        for (int x = ws; x < we; ++x) {
            s += row[x];
        }
    }

    int area = (he - hs) * (we - ws);
    out[(size_t)r * C_ + c] = (area > 0) ? s / (float)area : 0.0f;
}

extern "C" void kernel_launch(void* const* d_in, const int* in_sizes, int n_in,
                              void* d_out, int out_size, void* d_ws, size_t ws_size,
                              hipStream_t stream) {
    const float* fsam = (const float*)d_in[0];
    const float* box  = (const float*)d_in[1];
    float* out = (float*)d_out;

    // 8 XCD-slots x 1024 (2 channel-groups x 16 ch x 32 rblocks); a few
    // padding blocks (group 15 has only 5 valid channels) exit early.
    psroi_kernel<<<8192, 256, 0, stream>>>(fsam, box, out);
}

// Round 12
// 59.813 us; speedup vs baseline: 3.4580x; 1.7391x over previous
//
#include <hip/hip_runtime.h>

// PSROI pooling: fsam (N=8, C=245, H=80, W=80) f32, box (R=8192, 5) f32
// out (R, 245) f32. out[r, c] = mean over fsam[b, c, hs:he, ws:we].
//
// ARITHMETIC (frozen since R10, DO NOT TOUCH): bin = roi * fl32(1/7)
// (reciprocal multiply, 0x3E124925) and edges = SEPARATELY-rounded
// g*bin + off (asm barriers). Matches ref (absmax 0.015625 <= 0.0725).
//
// R12: two-kernel SAT path. R11 was gather-latency-bound (dur 104us, HBM
// 5%, VALUBusy 10%): divergent bin loops -> ~16 wave-iterations x 64
// scattered lines each. Kernel1 builds the reference's padded 81x81
// summed-area table per (n,c) plane into d_ws (1960 x 26.2KB = 49.1MB);
// kernel2 = frozen edges + bin_sum from 4 uniform gathers (no divergence),
// ~4x fewer TA line-fetches. SAT also matches ref numerics more closely.

#define N_ 8
#define C_ 245
#define H_ 80
#define W_ 80
#define R_ 8192
#define P_ 7
#define SATW 81
#define SATSZ (SATW * SATW)            // 6561 floats per plane
#define NPLANES (N_ * C_)              // 1960

// XLA-style separately-rounded a*b + c in f32; barriers forbid contraction.
__device__ __forceinline__ float sep_ma(float a, float b, float c) {
    float p = a * b;                 // v_mul_f32, IEEE RN
    asm volatile("" : "+v"(p));      // contraction barrier
    float s = p + c;                 // v_add_f32, IEEE RN
    asm volatile("" : "+v"(s));
    return s;
}

// ---------------- kernel 1: build padded SAT per (n,c) plane ----------------
__global__ __launch_bounds__(256) void sat_kernel(
    const float* __restrict__ fsam,
    float* __restrict__ sat)
{
    __shared__ float buf[H_ * (W_ + 1)];          // 80 x 81 (pad: bank-safe)
    int plane = blockIdx.x;                        // 0..1959
    int tid = threadIdx.x;

    const float* src = fsam + (size_t)plane * (H_ * W_);
    // coalesced load into LDS
    for (int i = tid; i < H_ * W_; i += 256)
        buf[(i / W_) * (W_ + 1) + (i % W_)] = src[i];
    __syncthreads();

    // row-wise cumsum (horizontal), one thread per row
    if (tid < H_) {
        float run = 0.0f;
        int base = tid * (W_ + 1);
        for (int x = 0; x < W_; ++x) {
            run += buf[base + x];
            buf[base + x] = run;
        }
    }
    __syncthreads();

    // column-wise cumsum (vertical) + write padded SAT rows coalesced.
    // S[0][*] = 0, S[*][0] = 0; S[y+1][j] = sum_{rows<=y} rowcum[row][j-1].
    float* dst = sat + (size_t)plane * SATSZ;
    if (tid < SATW) {
        int j = tid;
        float run = 0.0f;
        dst[j] = 0.0f;                              // row 0
        for (int y = 0; y < H_; ++y) {
            if (j > 0) run += buf[y * (W_ + 1) + (j - 1)];
            dst[(y + 1) * SATW + j] = run;          // coalesced across j
        }
    }
}

// ---------------- kernel 2: pool from SAT (frozen edge math) ----------------
__global__ __launch_bounds__(256) void psroi_sat_kernel(
    const float* __restrict__ sat,
    const float* __restrict__ box,
    float* __restrict__ out)
{
    // swizzled block decode (R11): XCD j <- channel groups {j, j+8}
    int id = blockIdx.x;
    int j  = id & 7;
    int m  = id >> 3;
    int g  = (m < 512) ? j : j + 8;
    int l  = (m < 512) ? m : m - 512;
    int c    = g * 16 + (l >> 5);
    int rblk = l & 31;
    if (c >= C_) return;

    int r = rblk * 256 + (int)threadIdx.x;
    int pw = c % P_;
    int ph = (c / P_) % P_;

    // ---- R10-frozen edge arithmetic ----
    const float* bx = box + (size_t)r * 5;
    int   b  = (int)bx[0];
    float x1 = rintf(bx[1]);
    float y1 = rintf(bx[2]);
    float x2 = rintf(bx[3] + 1.0f);
    float y2 = rintf(bx[4] + 1.0f);

    float roi_w = fmaxf(x2 - x1, 0.1f);
    float roi_h = fmaxf(y2 - y1, 0.1f);

    const float RCP7 = __uint_as_float(0x3E124925u);  // fl32(1/7), rounds up
    float bin_w = roi_w * RCP7;
    float bin_h = roi_h * RCP7;
    asm volatile("" : "+v"(bin_w), "+v"(bin_h));

    float hs_f = floorf(sep_ma((float)ph,       bin_h, y1));
    float he_f = ceilf (sep_ma((float)(ph + 1), bin_h, y1));
    float ws_f = floorf(sep_ma((float)pw,       bin_w, x1));
    float we_f = ceilf (sep_ma((float)(pw + 1), bin_w, x1));

    int hs = (int)fminf(fmaxf(hs_f, 0.0f), 80.0f);
    int he = (int)fminf(fmaxf(he_f, 0.0f), 80.0f);
    int ws = (int)fminf(fmaxf(ws_f, 0.0f), 80.0f);
    int we = (int)fminf(fmaxf(we_f, 0.0f), 80.0f);

    // ---- bin sum from SAT: 4 uniform gathers, ref op order ----
    const float* S = sat + ((size_t)b * C_ + c) * SATSZ;
    float s11 = S[he * SATW + we];
    float s01 = S[hs * SATW + we];
    float s10 = S[he * SATW + ws];
    float s00 = S[hs * SATW + ws];
    float bin_sum = ((s11 - s01) - s10) + s00;

    int area = (he - hs) * (we - ws);
    out[(size_t)r * C_ + c] = (area > 0) ? bin_sum / (float)area : 0.0f;
}

// ---------------- fallback: R11 direct-sum kernel (ws too small) -----------
__global__ __launch_bounds__(256) void psroi_direct_kernel(
    const float* __restrict__ fsam,
    const float* __restrict__ box,
    float* __restrict__ out)
{
    int id = blockIdx.x;
    int j  = id & 7;
    int m  = id >> 3;
    int g  = (m < 512) ? j : j + 8;
    int l  = (m < 512) ? m : m - 512;
    int c    = g * 16 + (l >> 5);
    int rblk = l & 31;
    if (c >= C_) return;

    int r = rblk * 256 + (int)threadIdx.x;
    int pw = c % P_;
    int ph = (c / P_) % P_;

    const float* bx = box + (size_t)r * 5;
    int   b  = (int)bx[0];
    float x1 = rintf(bx[1]);
    float y1 = rintf(bx[2]);
    float x2 = rintf(bx[3] + 1.0f);
    float y2 = rintf(bx[4] + 1.0f);

    float roi_w = fmaxf(x2 - x1, 0.1f);
    float roi_h = fmaxf(y2 - y1, 0.1f);

    const float RCP7 = __uint_as_float(0x3E124925u);
    float bin_w = roi_w * RCP7;
    float bin_h = roi_h * RCP7;
    asm volatile("" : "+v"(bin_w), "+v"(bin_h));

    float hs_f = floorf(sep_ma((float)ph,       bin_h, y1));
    float he_f = ceilf (sep_ma((float)(ph + 1), bin_h, y1));
    float ws_f = floorf(sep_ma((float)pw,       bin_w, x1));
    float we_f = ceilf (sep_ma((float)(pw + 1), bin_w, x1));

    int hs = (int)fminf(fmaxf(hs_f, 0.0f), 80.0f);
    int he = (int)fminf(fmaxf(he_f, 0.0f), 80.0f);
    int ws = (int)fminf(fmaxf(ws_f, 0.0f), 80.0f);
    int we = (int)fminf(fmaxf(we_f, 0.0f), 80.0f);

    const float* plane = fsam + ((size_t)b * C_ + c) * (H_ * W_);
    float s = 0.0f;
    for (int y = hs; y < he; ++y) {
        const float* row = plane + y * W_;
        for (int x = ws; x < we; ++x) s += row[x];
    }
    int area = (he - hs) * (we - ws);
    out[(size_t)r * C_ + c] = (area > 0) ? s / (float)area : 0.0f;
}

extern "C" void kernel_launch(void* const* d_in, const int* in_sizes, int n_in,
                              void* d_out, int out_size, void* d_ws, size_t ws_size,
                              hipStream_t stream) {
    const float* fsam = (const float*)d_in[0];
    const float* box  = (const float*)d_in[1];
    float* out = (float*)d_out;

    size_t sat_bytes = (size_t)NPLANES * SATSZ * sizeof(float);  // 49.1 MB
    if (ws_size >= sat_bytes) {
        float* sat = (float*)d_ws;
        sat_kernel<<<NPLANES, 256, 0, stream>>>(fsam, sat);
        psroi_sat_kernel<<<8192, 256, 0, stream>>>(sat, box, out);
    } else {
        psroi_direct_kernel<<<8192, 256, 0, stream>>>(fsam, box, out);
    }
}